// Round 4
// baseline (1244.772 us; speedup 1.0000x reference)
//
#include <hip/hip_runtime.h>

typedef _Float16 half_t;

#define N_SRCN 50000
#define N_DSTN 50000
#define NE     1600000
#define IN_DIM 128
#define OUT_DIMN 128
#define EDGE_DIMN 64
#define NHEAD  4
#define HDIM   32

// 16-lane (DPP row) rotate-add full reduction: after 4 steps every lane in each
// 16-lane row holds the row's sum. Pure VALU — no LDS/DS ops.
#define ROR_ADD(x, CTRL) ((x) + __int_as_float(__builtin_amdgcn_update_dpp( \
    0, __float_as_int(x), (CTRL), 0xF, 0xF, false)))
__device__ __forceinline__ float sum16(float s) {
    s = ROR_ADD(s, 0x121);  // row_ror:1
    s = ROR_ADD(s, 0x122);  // row_ror:2
    s = ROR_ADD(s, 0x124);  // row_ror:4
    s = ROR_ADD(s, 0x128);  // row_ror:8
    return s;
}

// ---------------------------------------------------------------------------
// Workspace layout — 15,205,392 bytes total (< 15,206,144 proven safe).
//   ssrc   u16[1.6M]      @ 0           (3,200,000)  src ids, dst-sorted
//   wA     f16[1.6M]      @ 3,200,000   (3,200,000)  exp-weights head A, dst-sorted
//   wB     f16[1.6M]      @ 6,400,000   (3,200,000)  exp-weights head B, dst-sorted
//   hs_q   f16[50000*32]  @ 9,600,000   (3,200,000)  quarter of h_src @ W_src
//   esrc   f32[200,000]   @ 12,800,000  (  800,000)  per-src logits [N,4]
//   edstl  f32[200,000]   @ 13,600,000  (  800,000)  per-dst logits [N,4]
//   offs   i32[50001]     @ 14,400,000  (  200,016)  CSR row offsets
//   curA   i32[50000]     @ 14,600,016  (  200,000)  cursor for stream pass A
//   curB   i32[50000]     @ 14,800,016  (  200,000)  cursor for stream pass B
//   counts i32[50000]     @ 15,000,016  (  200,000)  degree histogram
//   c_srcH f32[512]       @ 15,200,016  (    2,048)  head-major [h*128+k]
//   c_dstH f32[512]       @ 15,202,064  (    2,048)
//   c_edgeH f32[256]      @ 15,204,112  (    1,024)  head-major [h*64+k]
//   bsum   i32[64]        @ 15,205,136  (      256)  scan block sums
// ---------------------------------------------------------------------------

// K1: fold attention vectors through weights (head-major outputs).
__global__ __launch_bounds__(512) void k_combine(
    const float* __restrict__ Wsrc, const float* __restrict__ Wdst,
    const float* __restrict__ Wedge,
    const float* __restrict__ asrc, const float* __restrict__ adst,
    const float* __restrict__ aedge,
    float* __restrict__ c_srcH, float* __restrict__ c_dstH,
    float* __restrict__ c_edgeH) {
    int t = threadIdx.x;           // k = t>>2 (0..127), h = t&3
    int k = t >> 2, h = t & 3;
    float s1 = 0.f, s2 = 0.f;
    #pragma unroll
    for (int d = 0; d < HDIM; ++d) {
        s1 += Wsrc[k * OUT_DIMN + h * HDIM + d] * asrc[h * HDIM + d];
        s2 += Wdst[k * OUT_DIMN + h * HDIM + d] * adst[h * HDIM + d];
    }
    c_srcH[h * IN_DIM + k] = s1;
    c_dstH[h * IN_DIM + k] = s2;
    if (t < EDGE_DIMN * NHEAD) {   // k = 0..63
        float s3 = 0.f;
        #pragma unroll
        for (int d = 0; d < HDIM; ++d)
            s3 += Wedge[k * OUT_DIMN + h * HDIM + d] * aedge[h * HDIM + d];
        c_edgeH[h * EDGE_DIMN + k] = s3;  // [h*64+k]
    }
}

// K2: node logits for BOTH src and dst in one launch.
// Blocks 0..3124 -> src rows, 3125..6249 -> dst rows (uniform per block).
// 16 lanes per row (2 float4 each), DPP reduce, all 4 heads.
__global__ __launch_bounds__(256) void k_node_logits2(
    const float* __restrict__ Xs, const float* __restrict__ Xd,
    const float* __restrict__ cSH, const float* __restrict__ cDH,
    float* __restrict__ esrc, float* __restrict__ edstl) {
    int b = blockIdx.x;
    bool isSrc = b < 3125;
    const float* X = isSrc ? Xs : Xd;
    const float* cH = isSrc ? cSH : cDH;
    float* outl = isSrc ? esrc : edstl;
    int t = threadIdx.x;
    int row = (isSrc ? b : b - 3125) * 16 + (t >> 4);
    int q = t & 15;
    const float4* X4 = (const float4*)X;
    const float4* C4 = (const float4*)cH;
    float4 xa = X4[(size_t)row * 32 + q];
    float4 xb = X4[(size_t)row * 32 + 16 + q];
    float s0, s1, s2, s3;
    #pragma unroll
    for (int h = 0; h < 4; ++h) {
        float4 ca = C4[h * 32 + q];
        float4 cb = C4[h * 32 + 16 + q];
        float v = xa.x * ca.x + xa.y * ca.y + xa.z * ca.z + xa.w * ca.w
                + xb.x * cb.x + xb.y * cb.y + xb.z * cb.z + xb.w * cb.w;
        v = sum16(v);
        if (h == 0) s0 = v; else if (h == 1) s1 = v;
        else if (h == 2) s2 = v; else s3 = v;
    }
    float v = (q == 0) ? s0 : (q == 1) ? s1 : (q == 2) ? s2 : s3;
    if (q < 4) outl[(size_t)row * 4 + q] = v;
}

// K3a: degree histogram over dst indices.
__global__ __launch_bounds__(256) void k_hist(
    const int* __restrict__ dstI, int* __restrict__ counts) {
    int e = blockIdx.x * 256 + threadIdx.x;
    if (e < NE) atomicAdd(&counts[dstI[e]], 1);
}

// K3b-1: per-block (1024-wide) exclusive scan, block totals to bsum.
__global__ __launch_bounds__(1024) void k_scan_part(
    const int* __restrict__ cnt, int* __restrict__ offs, int* __restrict__ bsum) {
    __shared__ int wsum[16];
    int t = threadIdx.x, b = blockIdx.x;
    int idx = b * 1024 + t;
    int lane = t & 63, w = t >> 6;
    int c = (idx < N_DSTN) ? cnt[idx] : 0;
    int incl = c;
    #pragma unroll
    for (int off = 1; off < 64; off <<= 1) {
        int v = __shfl_up(incl, off, 64);
        if (lane >= off) incl += v;
    }
    if (lane == 63) wsum[w] = incl;
    __syncthreads();
    if (t == 0) {
        int run = 0;
        #pragma unroll
        for (int qq = 0; qq < 16; ++qq) { int v = wsum[qq]; wsum[qq] = run; run += v; }
        bsum[b] = run;
    }
    __syncthreads();
    if (idx < N_DSTN) offs[idx] = wsum[w] + incl - c;
}

// K3b-2: exclusive scan of the 49 block sums; writes grand total to offs[N].
__global__ __launch_bounds__(64) void k_scan_mid(
    int* __restrict__ bsum, int* __restrict__ offs, int nb) {
    int l = threadIdx.x;
    int v = (l < nb) ? bsum[l] : 0;
    int incl = v;
    #pragma unroll
    for (int off = 1; off < 64; off <<= 1) {
        int u = __shfl_up(incl, off, 64);
        if (l >= off) incl += u;
    }
    if (l < nb) bsum[l] = incl - v;
    if (l == 63) offs[N_DSTN] = incl;
}

// K3b-3: add block base, copy to both cursors.
__global__ __launch_bounds__(1024) void k_scan_add(
    int* __restrict__ offs, int* __restrict__ curA, int* __restrict__ curB,
    const int* __restrict__ bsum) {
    int idx = blockIdx.x * 1024 + threadIdx.x;
    if (idx < N_DSTN) {
        int v = offs[idx] + bsum[blockIdx.x];
        offs[idx] = v;
        curA[idx] = v;
        curB[idx] = v;
    }
}

// K4: streaming edge pass for heads (ha, hb). 16 lanes per edge, coalesced EF
// read (1KB per wave), DPP dot for both heads, exp, then scatter
// (u16 src, fp16 wA, fp16 wB) to the dst-sorted slot via atomic cursor.
__global__ __launch_bounds__(256) void k_edge_stream(
    const float* __restrict__ EF,
    const int* __restrict__ srcI, const int* __restrict__ dstI,
    const float* __restrict__ esrc, const float* __restrict__ edstl,
    const float* __restrict__ ceH, int* __restrict__ cursor,
    unsigned short* __restrict__ ssrc,
    half_t* __restrict__ wAo, half_t* __restrict__ wBo,
    int ha, int hb) {
    int t = threadIdx.x;
    int e = blockIdx.x * 16 + (t >> 4);
    if (e >= NE) return;
    int q = t & 15;
    const float4* EF4 = (const float4*)EF;
    const float4* CE4 = (const float4*)ceH;
    float4 v  = EF4[(size_t)e * 16 + q];
    float4 cA = CE4[ha * 16 + q];
    float4 cB = CE4[hb * 16 + q];
    float sA = v.x * cA.x + v.y * cA.y + v.z * cA.z + v.w * cA.w;
    float sB = v.x * cB.x + v.y * cB.y + v.z * cB.z + v.w * cB.w;
    sA = sum16(sA);
    sB = sum16(sB);   // all 16 lanes hold both head dots
    int pos = 0;
    if (q < 2) {
        int si = srcI[e], di = dstI[e];
        int h = q ? hb : ha;
        float s = q ? sB : sA;
        float z = esrc[(size_t)si * 4 + h] + edstl[(size_t)di * 4 + h] + s;
        z = z > 0.f ? z : 0.2f * z;
        float ez = __expf(z);
        if (q == 0) pos = atomicAdd(&cursor[di], 1);
        pos = __shfl(pos, (t & 63) & ~15, 64);   // broadcast from group lane 0
        if (q == 0) {
            ssrc[pos] = (unsigned short)si;
            wAo[pos] = (half_t)ez;
        } else {
            wBo[pos] = (half_t)ez;
        }
    }
}

// K5: hs_q = (h_src @ W_src)[:, c0:c0+32], stored fp16. M=64/block, N=32.
__global__ __launch_bounds__(256) void k_gemm_q(
    const float* __restrict__ A, const float* __restrict__ W,
    half_t* __restrict__ C, int M, int c0) {
    __shared__ float As[64][68];
    __shared__ float Ws[64][36];
    int t = threadIdx.x;
    int tx = t & 7, ty = t >> 3;   // tx: 8 col slots, ty: 32 row slots
    int rowbase = blockIdx.x * 64;
    float acc[2][4];
    #pragma unroll
    for (int i = 0; i < 2; ++i)
        #pragma unroll
        for (int j = 0; j < 4; ++j) acc[i][j] = 0.f;

    for (int kc = 0; kc < IN_DIM; kc += 64) {
        #pragma unroll
        for (int p = 0; p < 4; ++p) {          // A tile: 64x64
            int flat = p * 1024 + t * 4;
            int r = flat >> 6, ck = flat & 63;
            float4 v = make_float4(0.f, 0.f, 0.f, 0.f);
            if (rowbase + r < M)
                v = *(const float4*)(A + (size_t)(rowbase + r) * IN_DIM + kc + ck);
            *(float4*)(&As[r][ck]) = v;
        }
        #pragma unroll
        for (int p = 0; p < 2; ++p) {          // W tile: 64x32 (cols c0..c0+31)
            int flat = p * 1024 + t * 4;
            int kk = flat >> 5, col = flat & 31;
            *(float4*)(&Ws[kk][col]) =
                *(const float4*)(W + (size_t)(kc + kk) * OUT_DIMN + c0 + col);
        }
        __syncthreads();
        #pragma unroll
        for (int k = 0; k < 64; ++k) {
            float a[2], b[4];
            #pragma unroll
            for (int i = 0; i < 2; ++i) a[i] = As[ty * 2 + i][k];
            #pragma unroll
            for (int j = 0; j < 4; ++j) b[j] = Ws[k][tx + j * 8];
            #pragma unroll
            for (int i = 0; i < 2; ++i)
                #pragma unroll
                for (int j = 0; j < 4; ++j) acc[i][j] += a[i] * b[j];
        }
        __syncthreads();
    }
    #pragma unroll
    for (int i = 0; i < 2; ++i) {
        int row = rowbase + ty * 2 + i;
        if (row < M) {
            #pragma unroll
            for (int j = 0; j < 4; ++j)
                C[(size_t)row * 32 + tx + j * 8] = (half_t)acc[i][j];
        }
    }
}

// K6: gather for one head. TWO waves per dst, each wave's 32-lane halves own
// one quarter of the edge list (serial depth n/4 ~ 8). Depth-4 pipeline on the
// (ssrc,w) streams, depth-2 on the hs_q gather (address known 2 iters early).
// Lane owns col hcol + (l&31); intra-wave combine via shfl_xor(32), cross-wave
// via 1KB LDS. No early returns (all threads reach the barrier).
__global__ __launch_bounds__(256) void k_gather(
    const int* __restrict__ offs, const unsigned short* __restrict__ ssrc,
    const half_t* __restrict__ wH, const half_t* __restrict__ hs_q,
    float* __restrict__ out, int hcol) {
    __shared__ float sacc[2][2][32];
    __shared__ float sden[2][2][32];
    int t = threadIdx.x;
    int wid = t >> 6;              // 0..3
    int dp = wid >> 1;             // which dst of the pair
    int sub = wid & 1;             // which wave for this dst
    int l = t & 63;
    int half = l >> 5, c = l & 31;
    int d = blockIdx.x * 2 + dp;
    bool valid = d < N_DSTN;
    int start = 0, n = 0;
    if (valid) { start = offs[d]; n = offs[d + 1] - start; }
    int q4 = sub * 2 + half;       // quarter 0..3
    int n4 = n >> 2, rem = n & 3;
    int myN = n4 + (q4 < rem ? 1 : 0);
    int myStart = start + q4 * n4 + (q4 < rem ? q4 : rem);
    int lim = (myN > 0) ? (myN - 1) : 0;
    float acc = 0.f, den = 0.f;
    if (valid && n > 0) {
        #define RIDX(j) (myStart + (((j) < lim) ? (j) : lim))
        int s0 = ssrc[RIDX(0)], s1 = ssrc[RIDX(1)];
        int s2 = ssrc[RIDX(2)], s3 = ssrc[RIDX(3)];
        half_t w0 = wH[RIDX(0)], w1 = wH[RIDX(1)];
        half_t w2 = wH[RIDX(2)], w3 = wH[RIDX(3)];
        half_t h0 = hs_q[(size_t)s0 * 32 + c];
        half_t h1 = hs_q[(size_t)s1 * 32 + c];
        int cnt = n4 + (rem ? 1 : 0);   // uniform loop count across quarters
        for (int j = 0; j < cnt; ++j) {
            int sN = ssrc[RIDX(j + 4)];
            half_t wN = wH[RIDX(j + 4)];
            half_t hN = hs_q[(size_t)s2 * 32 + c];   // s2 = s_{j+2}, arrived
            float wf = (j < myN) ? (float)w0 : 0.f;
            den += wf;
            acc = fmaf(wf, (float)h0, acc);
            s0 = s1; s1 = s2; s2 = s3; s3 = sN;
            w0 = w1; w1 = w2; w2 = w3; w3 = wN;
            h0 = h1; h1 = hN;
        }
        #undef RIDX
        acc += __shfl_xor(acc, 32, 64);
        den += __shfl_xor(den, 32, 64);
    }
    if (l < 32) { sacc[dp][sub][c] = acc; sden[dp][sub][c] = den; }
    __syncthreads();
    if (sub == 0 && l < 32 && valid) {
        float a  = sacc[dp][0][c] + sacc[dp][1][c];
        float dn = sden[dp][0][c] + sden[dp][1][c];
        out[(size_t)d * OUT_DIMN + hcol + c] = (n > 0) ? a / (dn + 1e-8f) : 0.f;
    }
}

extern "C" void kernel_launch(void* const* d_in, const int* in_sizes, int n_in,
                              void* d_out, int out_size, void* d_ws, size_t ws_size,
                              hipStream_t stream) {
    const float* h_src     = (const float*)d_in[0];
    const float* h_dst     = (const float*)d_in[1];
    const float* edge_feat = (const float*)d_in[2];
    const int*   eidx      = (const int*)d_in[3];   // [2, E] int32
    const float* Wsrc      = (const float*)d_in[4];
    const float* Wdst      = (const float*)d_in[5];
    const float* Wedge     = (const float*)d_in[6];
    const float* asrc      = (const float*)d_in[7];
    const float* adst      = (const float*)d_in[8];
    const float* aedge     = (const float*)d_in[9];
    float* out = (float*)d_out;

    char* W = (char*)d_ws;
    unsigned short* ssrc = (unsigned short*)(W + 0);
    half_t* wA     = (half_t*)(W + 3200000);
    half_t* wB     = (half_t*)(W + 6400000);
    half_t* hs_q   = (half_t*)(W + 9600000);
    float* esrc    = (float*)(W + 12800000);
    float* edstl   = (float*)(W + 13600000);
    int*   offs    = (int*)(W + 14400000);
    int*   curA    = (int*)(W + 14600016);
    int*   curB    = (int*)(W + 14800016);
    int*   counts  = (int*)(W + 15000016);
    float* c_srcH  = (float*)(W + 15200016);
    float* c_dstH  = (float*)(W + 15202064);
    float* c_edgeH = (float*)(W + 15204112);
    int*   bsum    = (int*)(W + 15205136);

    const int* srcI = eidx;
    const int* dstI = eidx + NE;

    const int NB_SCAN = (N_DSTN + 1023) / 1024;   // 49

    hipMemsetAsync(counts, 0, N_DSTN * sizeof(int), stream);

    k_combine<<<1, 512, 0, stream>>>(Wsrc, Wdst, Wedge, asrc, adst, aedge,
                                     c_srcH, c_dstH, c_edgeH);
    k_node_logits2<<<6250, 256, 0, stream>>>(h_src, h_dst, c_srcH, c_dstH,
                                             esrc, edstl);

    k_hist<<<(NE + 255) / 256, 256, 0, stream>>>(dstI, counts);
    k_scan_part<<<NB_SCAN, 1024, 0, stream>>>(counts, offs, bsum);
    k_scan_mid<<<1, 64, 0, stream>>>(bsum, offs, NB_SCAN);
    k_scan_add<<<NB_SCAN, 1024, 0, stream>>>(offs, curA, curB, bsum);

    // heads 0,1
    k_edge_stream<<<(NE + 15) / 16, 256, 0, stream>>>(
        edge_feat, srcI, dstI, esrc, edstl, c_edgeH, curA, ssrc, wA, wB, 0, 1);
    k_gemm_q<<<(N_SRCN + 63) / 64, 256, 0, stream>>>(h_src, Wsrc, hs_q, N_SRCN, 0);
    k_gather<<<(N_DSTN + 1) / 2, 256, 0, stream>>>(offs, ssrc, wA, hs_q, out, 0);
    k_gemm_q<<<(N_SRCN + 63) / 64, 256, 0, stream>>>(h_src, Wsrc, hs_q, N_SRCN, 32);
    k_gather<<<(N_DSTN + 1) / 2, 256, 0, stream>>>(offs, ssrc, wB, hs_q, out, 32);

    // heads 2,3 (rewrites ssrc/wA/wB with pass-B ordering — consistent within pass)
    k_edge_stream<<<(NE + 15) / 16, 256, 0, stream>>>(
        edge_feat, srcI, dstI, esrc, edstl, c_edgeH, curB, ssrc, wA, wB, 2, 3);
    k_gemm_q<<<(N_SRCN + 63) / 64, 256, 0, stream>>>(h_src, Wsrc, hs_q, N_SRCN, 64);
    k_gather<<<(N_DSTN + 1) / 2, 256, 0, stream>>>(offs, ssrc, wA, hs_q, out, 64);
    k_gemm_q<<<(N_SRCN + 63) / 64, 256, 0, stream>>>(h_src, Wsrc, hs_q, N_SRCN, 96);
    k_gather<<<(N_DSTN + 1) / 2, 256, 0, stream>>>(offs, ssrc, wB, hs_q, out, 96);
}